// Round 11
// baseline (905.144 us; speedup 1.0000x reference)
//
#include <hip/hip_runtime.h>
#include <hip/hip_bf16.h>
#include <hip/hip_fp16.h>
#include <stdint.h>

// Problem constants (QLoRALinear_34454227649197)
#define M_DIM 16384   // TOK
#define N_DIM 4096    // OUT
#define K_DIM 4096    // IN
#define NGROUP 64     // K_DIM / 64
#define NT    64      // K-tiles (K_DIM / 64), even

// Harness dtype note (round-3 forensics): float16 arrays are presented as
// FLOAT32 on device. x = const float*, out = float*.

typedef _Float16 f16x8 __attribute__((ext_vector_type(8)));
typedef _Float16 f16x2 __attribute__((ext_vector_type(2)));
typedef float f32x4 __attribute__((ext_vector_type(4)));

typedef __attribute__((address_space(3))) uint32_t lds_u32_t;
typedef const __attribute__((address_space(1))) uint32_t glob_u32_t;

__device__ __forceinline__ void gload16(const void* g, void* l) {
    // global_load_lds_dwordx4: LDS dest = wave-uniform base + lane*16;
    // global source per-lane (pre-swizzled). Zero conflicts rounds 5-10.
    __builtin_amdgcn_global_load_lds((glob_u32_t*)g, (lds_u32_t*)l, 16, 0, 0);
}

// ---------------------------------------------------------------------------
// Kernel 0: Xh[i] = (fp16) x[i]   (exact: x values are fp16-quantized)
// ---------------------------------------------------------------------------
__global__ __launch_bounds__(256) void convert_x_kernel(
    const float* __restrict__ x, _Float16* __restrict__ Xh)
{
    const size_t i = ((size_t)blockIdx.x * 256 + threadIdx.x) * 8;
    const float4 a = *reinterpret_cast<const float4*>(&x[i]);
    const float4 b = *reinterpret_cast<const float4*>(&x[i + 4]);
    f16x8 o;
    o[0] = (_Float16)a.x; o[1] = (_Float16)a.y;
    o[2] = (_Float16)a.z; o[3] = (_Float16)a.w;
    o[4] = (_Float16)b.x; o[5] = (_Float16)b.y;
    o[6] = (_Float16)b.z; o[7] = (_Float16)b.w;
    *reinterpret_cast<f16x8*>(&Xh[i]) = o;
}

// ---------------------------------------------------------------------------
// Kernel 1: W[local n][k] = (q[n0+n][k]-8)*scales[n0+n][k/64]
//                           + sum_r lB[n0+n][r]*lA[r][k]     (fp16 out)
// ---------------------------------------------------------------------------
__global__ __launch_bounds__(256) void dequant_lora_kernel(
    const int* __restrict__ q, const float* __restrict__ sc,
    const float* __restrict__ lA, const float* __restrict__ lB,
    _Float16* __restrict__ W, int n0)
{
    const int t   = threadIdx.x;
    const int o0l = blockIdx.x * 4;        // local chunk row base
    const int o0g = n0 + o0l;              // global OUT row base

    __shared__ float sScale[4][64];
    __shared__ float sB[4][16];
    sScale[t >> 6][t & 63] = sc[(size_t)(o0g + (t >> 6)) * NGROUP + (t & 63)];
    if (t < 64) sB[t >> 4][t & 15] = lB[(size_t)(o0g + (t >> 4)) * 16 + (t & 15)];
    __syncthreads();

    for (int j = 0; j < 8; ++j) {
        const int i = j * 512 + t * 2;      // even; covers [0,4096)
        float l0[4] = {0.f, 0.f, 0.f, 0.f};
        float l1[4] = {0.f, 0.f, 0.f, 0.f};
        #pragma unroll
        for (int r = 0; r < 16; ++r) {
            const float2 a = *reinterpret_cast<const float2*>(&lA[(size_t)r * K_DIM + i]);
            #pragma unroll
            for (int row = 0; row < 4; ++row) {
                l0[row] = fmaf(sB[row][r], a.x, l0[row]);
                l1[row] = fmaf(sB[row][r], a.y, l1[row]);
            }
        }
        const int g = i >> 6;               // i even => i, i+1 same group
        #pragma unroll
        for (int row = 0; row < 4; ++row) {
            const int2 qv = *reinterpret_cast<const int2*>(&q[(size_t)(o0g + row) * K_DIM + i]);
            const float s = sScale[row][g];
            f16x2 h2;
            h2[0] = (_Float16)fmaf((float)(qv.x - 8), s, l0[row]);
            h2[1] = (_Float16)fmaf((float)(qv.y - 8), s, l1[row]);
            *reinterpret_cast<f16x2*>(&W[(size_t)(o0l + row) * K_DIM + i]) = h2;
        }
    }
}

// ---------------------------------------------------------------------------
// Kernel 2: out = Xh @ W^T — 256x256, BK=64, 8 waves (2M x 4N, 128x64/wave).
// Rounds 5-10 all plateau at ~1.0 PF: per tile LDS-reads (2304cy) + MFMA
// (2483cy) SERIALIZE (measured ~sum). Fix: B-operand bypasses LDS entirely
// (global->reg, 8 loads/wave/tile, preloaded ONE TILE ahead via even/odd
// named reg sets; B is L2-hot). A stays LDS-staged (4x wave reuse).
// LDS pipe/tile drops to ~1800cy < MFMA 2483cy. Single __syncthreads/tile
// (R7 style): every outstanding load at the drain was issued >= 1 full tile
// (~2500cy) earlier -> drain ~free. No asm vmcnt (no mixed-count fragility).
// ---------------------------------------------------------------------------
#define ABUF_BYTES 32768              // A buffer: 256 rows x 128 B

__global__ __launch_bounds__(512, 2) void gemm_bt_kernel(
    const _Float16* __restrict__ A,   // Xh chunk, [rows][K]
    const _Float16* __restrict__ B,   // W chunk,  [cols][K]
    float* __restrict__ C,
    int m0, int n0, int nbm, int nbn)
{
    alignas(16) __shared__ _Float16 lds[2 * 16384];   // 64 KiB (A only)

    const int t  = threadIdx.x;
    const int l  = t & 63;
    const int w  = t >> 6;          // 0..7
    const int wr = w >> 2;          // 0..1  (M: 128 rows)
    const int wc = w & 3;           // 0..3  (N: 64 cols)

    // m204 bijective XCD swizzle, then tail-safe GROUP_M=8.
    const int nwg  = nbm * nbn;
    const int orig = blockIdx.x;
    const int xcd  = orig & 7;
    const int qq = nwg >> 3, rr = nwg & 7;
    const int wg = (xcd < rr ? xcd * (qq + 1) : rr * (qq + 1) + (xcd - rr) * qq)
                 + (orig >> 3);
    const int gs    = 8 * nbn;
    const int group = wg / gs;
    const int start = group * 8;
    const int gsz   = (nbm - start < 8) ? (nbm - start) : 8;
    const int idg   = wg - group * gs;
    const int bm    = start + idg % gsz;
    const int bn    = idg / gsz;

    const int Mb = bm * 256;
    const int Nb = bn * 256;

    // A staging: 512 thr x 16B = 8 KB = 64 rows x 128 B per issue; 4 issues
    // per K-tile. Thread t -> row rloc = t>>3 (+n*64), phys slot t&7; source
    // k-off = ((t&7)^(rloc&7))*8 (inverse swizzle on global side).
    const int rloc = t >> 3;                   // 0..63
    const int kswz = ((t & 7) ^ (rloc & 7)) * 8;
    const _Float16* aSrc = A + (size_t)(Mb + rloc) * K_DIM + kswz;
    char* const ldsBase = (char*)lds;
    const int dOff = t * 16;

    const int r16 = l & 15;
    const int hi  = l >> 4;           // 0..3
    const int swzB = (r16 & 7) * 16;  // row-dependent XOR part (bytes)

    // B fragment base: lane reads B[Nb + wc*64 + i*16 + r16][k .. k+8).
    const _Float16* bBase = B + (size_t)(Nb + wc * 64 + r16) * K_DIM + hi * 8;

    f32x4 acc[8][4] = {};
    f16x8 bE[8], bO[8];   // even/odd tile B reg sets: [ks*4 + ni]

    // STAGE_A(kt1): DMA A tile kt1 into buf[kt1&1].
    auto STAGE_A = [&](int kt1) {
        char* d = ldsBase + (kt1 & 1) * ABUF_BYTES + dOff;
        const int kp = kt1 * 64;
        #pragma unroll
        for (int n = 0; n < 4; ++n)
            gload16(aSrc + (size_t)(n * 64) * K_DIM + kp, d + n * 8192);
    };

    // LOADB(dst, kt2): 8 reg loads covering this wave's B-quarter, K-tile kt2.
    #define LOADB(dst, kt2) do {                                            \
        _Pragma("unroll")                                                   \
        for (int ks_ = 0; ks_ < 2; ++ks_)                                   \
            _Pragma("unroll")                                               \
            for (int i_ = 0; i_ < 4; ++i_)                                  \
                dst[ks_ * 4 + i_] = *(const f16x8*)(bBase                   \
                    + (size_t)(i_ * 16) * K_DIM + (kt2) * 64 + ks_ * 32);   \
    } while (0)

    // COMPUTE(bufIdx, bSet): one K-tile of MFMA from LDS-A + reg-B.
    #define COMPUTE(bufIdx, bSet) do {                                      \
        const char* Ac = ldsBase + (bufIdx) * ABUF_BYTES;                   \
        _Pragma("unroll")                                                   \
        for (int ks = 0; ks < 2; ++ks) {                                    \
            _Pragma("unroll")                                               \
            for (int mq = 0; mq < 2; ++mq) {                                \
                f16x8 aF[4];                                                \
                const int swz = ((ks * 4 + hi) * 16) ^ swzB;                \
                _Pragma("unroll")                                           \
                for (int i = 0; i < 4; ++i)                                 \
                    aF[i] = *(const f16x8*)(Ac +                            \
                        (wr * 128 + mq * 64 + i * 16 + r16) * 128 + swz);   \
                __builtin_amdgcn_s_setprio(1);                              \
                _Pragma("unroll")                                           \
                for (int mi = 0; mi < 4; ++mi)                              \
                    _Pragma("unroll")                                       \
                    for (int ni = 0; ni < 4; ++ni)                          \
                        acc[mq * 4 + mi][ni] =                              \
                            __builtin_amdgcn_mfma_f32_16x16x32_f16(         \
                                aF[mi], bSet[ks * 4 + ni],                  \
                                acc[mq * 4 + mi][ni], 0, 0, 0);             \
                __builtin_amdgcn_s_setprio(0);                              \
            }                                                               \
        }                                                                   \
    } while (0)

    // Prologue: stage A(0), preload B(0) into even set.
    STAGE_A(0);
    LOADB(bE, 0);

    for (int kt = 0; kt < NT; kt += 2) {
        // EVEN tile kt: consume bE; prefetch kt+1 (A DMA + B regs).
        __syncthreads();              // publishes A[kt]; drain ~free (all
                                      // outstanding issued >= 1 tile ago)
        STAGE_A(kt + 1);              // kt+1 <= 63 always (NT even)
        LOADB(bO, kt + 1);
        COMPUTE(kt & 1, bE);

        // ODD tile kt+1: consume bO; prefetch kt+2.
        __syncthreads();
        if (kt + 2 < NT) {
            STAGE_A(kt + 2);
            LOADB(bE, kt + 2);
        }
        COMPUTE((kt + 1) & 1, bO);
    }

    // Epilogue: C/D layout col = lane&15, row = (lane>>4)*4 + reg. f32 stores.
    #pragma unroll
    for (int mi = 0; mi < 8; ++mi) {
        const int row0 = m0 + Mb + wr * 128 + mi * 16 + hi * 4;
        #pragma unroll
        for (int ni = 0; ni < 4; ++ni) {
            const int col = n0 + Nb + wc * 64 + ni * 16 + r16;
            const f32x4 v = acc[mi][ni];
            #pragma unroll
            for (int u = 0; u < 4; ++u)
                C[(size_t)(row0 + u) * N_DIM + col] = v[u];
        }
    }
    #undef LOADB
    #undef COMPUTE
}

extern "C" void kernel_launch(void* const* d_in, const int* in_sizes, int n_in,
                              void* d_out, int out_size, void* d_ws, size_t ws_size,
                              hipStream_t stream) {
    const float* x  = (const float*)d_in[0];   // fp16 values promoted to f32
    const int*   q  = (const int*)d_in[1];
    const float* sc = (const float*)d_in[2];
    const float* lA = (const float*)d_in[3];
    const float* lB = (const float*)d_in[4];
    float* out = (float*)d_out;                 // f32 output buffer

    // Workspace layout: [W: colC x K fp16][Xh: rowC x K fp16], chunk-looped.
    const size_t wfull = (size_t)N_DIM * K_DIM * 2;   // 32 MiB
    int colC, rowC;
    if (ws_size >= wfull + (size_t)256 * K_DIM * 2) {
        colC = N_DIM;
        size_t rows = (ws_size - wfull) / ((size_t)K_DIM * 2);
        rowC = (int)((rows / 256) * 256);
        if (rowC > M_DIM) rowC = M_DIM;
    } else {
        size_t half = ws_size / 2;
        colC = (int)((half / ((size_t)K_DIM * 2) / 256) * 256);
        if (colC < 256) colC = 256;
        if (colC > N_DIM) colC = N_DIM;
        size_t rows = (ws_size - (size_t)colC * K_DIM * 2) / ((size_t)K_DIM * 2);
        rowC = (int)((rows / 256) * 256);
        if (rowC < 256) rowC = 256;
        if (rowC > M_DIM) rowC = M_DIM;
    }
    _Float16* W  = (_Float16*)d_ws;
    _Float16* Xh = (_Float16*)d_ws + (size_t)colC * K_DIM;

    for (int n0 = 0; n0 < N_DIM; n0 += colC) {
        int cols = N_DIM - n0; if (cols > colC) cols = colC;
        dequant_lora_kernel<<<cols / 4, 256, 0, stream>>>(q, sc, lA, lB, W, n0);
        for (int m0 = 0; m0 < M_DIM; m0 += rowC) {
            int rows = M_DIM - m0; if (rows > rowC) rows = rowC;
            convert_x_kernel<<<(int)(((size_t)rows * K_DIM) / (256 * 8)), 256, 0, stream>>>(
                x + (size_t)m0 * K_DIM, Xh);
            gemm_bt_kernel<<<(rows / 256) * (cols / 256), 512, 0, stream>>>(
                Xh, W, out, m0, n0, rows / 256, cols / 256);
        }
    }
}